// Round 13
// baseline (1365.083 us; speedup 1.0000x reference)
//
#include <hip/hip_runtime.h>
#include <hip/hip_bf16.h>
#include <math.h>

// Problem constants
#define A_N    2000
#define P_N    20000
#define PPAD   20032   // P_N padded to 64 rows (out_transform tail)
#define E_N    200000
#define MUL0   128
#define MUL1   64
#define DIM    320     // MUL0 + 3*MUL1
#define NBASIS 10
#define FC_HID 100
#define WNUM   384     // 128+128+64+64
#define MID0   192     // MUL0 + MUL1
#define WSTR   394     // w_lds row stride (bf16): 788 B -> q-groups 2-way banks

// scales
#define RS10   0.31622776601683794f
#define RS100  0.1f
#define RS128  0.08838834764831845f
#define RS64   0.125f
#define RS192  0.07216878364870323f
#define RS3    0.5773502691896258f
#define RSNEI  0.31622776601683794f

typedef __bf16 bf16x8 __attribute__((ext_vector_type(8)));
typedef float  f32x4  __attribute__((ext_vector_type(4)));

__device__ __forceinline__ float bflo(unsigned u) { return __uint_as_float(u << 16); }
__device__ __forceinline__ float bfhi(unsigned u) { return __uint_as_float(u & 0xffff0000u); }
__device__ __forceinline__ unsigned pkbf(float lo, float hi) {
    __bf16 a = (__bf16)lo, b = (__bf16)hi;
    unsigned short ua = __builtin_bit_cast(unsigned short, a);
    unsigned short ub = __builtin_bit_cast(unsigned short, b);
    return (unsigned)ua | ((unsigned)ub << 16);
}

// ---------------------------------------------------------------------------
// Kernel 1: sender transform -> lane-blocked s_pack[a][64][6] bf16 (proven R8-R12)
// ---------------------------------------------------------------------------
__global__ __launch_bounds__(320) void sender_kernel(
    const float* __restrict__ sender_input, const float* __restrict__ sender_attr,
    const float* __restrict__ lin1_w0, const float* __restrict__ lin1_w1,
    __bf16* __restrict__ s_pack)
{
    __shared__ float sin_s[DIM];
    const int a = blockIdx.x;
    const int t = threadIdx.x;
    const float attr = sender_attr[a];
    sin_s[t] = sender_input[(size_t)a * DIM + t] * attr;
    __syncthreads();
    __bf16* row = s_pack + (size_t)a * 384;
    if (t < MUL0) {
        float acc = 0.f;
        for (int u = 0; u < MUL0; ++u)
            acc = fmaf(sin_s[u], lin1_w0[u * MUL0 + t], acc);
        row[(t & 63) * 6 + (t >> 6)] = (__bf16)(acc * RS128);
    } else {
        const int idx = t - MUL0;
        const int v = idx / 3, m = idx - 3 * v;
        float acc = 0.f;
        for (int u = 0; u < MUL1; ++u)
            acc = fmaf(sin_s[MUL0 + 3 * u + m], lin1_w1[u * MUL1 + v], acc);
        row[v * 6 + 2 + m] = (__bf16)(acc * RS64);
    }
    if (t < 64) row[t * 6 + 5] = (__bf16)0.f;
}

// ---------------------------------------------------------------------------
// CSR build: histogram -> scan -> scatter (+ permuted src/attr) (proven R8-R12)
// ---------------------------------------------------------------------------
__global__ __launch_bounds__(256) void hist_kernel(
    const int* __restrict__ edge_dst, int* __restrict__ counts)
{
    const int e = blockIdx.x * 256 + threadIdx.x;
    if (e < E_N) atomicAdd(&counts[edge_dst[e]], 1);
}

__global__ __launch_bounds__(1024) void scan_kernel(
    const int* __restrict__ counts, int* __restrict__ head)
{
    __shared__ int part[1024];
    const int t = threadIdx.x;
    const int base = t * 20;
    int c[20];
    int s = 0;
    #pragma unroll
    for (int i = 0; i < 20; ++i) {
        const int p = base + i;
        c[i] = (p < P_N) ? counts[p] : 0;
        s += c[i];
    }
    part[t] = s;
    __syncthreads();
    for (int off = 1; off < 1024; off <<= 1) {
        const int v = (t >= off) ? part[t - off] : 0;
        __syncthreads();
        part[t] += v;
        __syncthreads();
    }
    int run = (t > 0) ? part[t - 1] : 0;
    #pragma unroll
    for (int i = 0; i < 20; ++i) {
        const int p = base + i;
        if (p < P_N) { head[p] = run; run += c[i]; }
    }
}

__global__ __launch_bounds__(256) void scatter_kernel(
    const int* __restrict__ edge_dst, const int* __restrict__ edge_src,
    const float4* __restrict__ edge_attr4,
    int* __restrict__ head, int* __restrict__ sorted,
    int* __restrict__ src_sorted, float4* __restrict__ attr_sorted)
{
    const int e = blockIdx.x * 256 + threadIdx.x;
    if (e < E_N) {
        const int pos = atomicAdd(&head[edge_dst[e]], 1);
        sorted[pos]      = e;
        src_sorted[pos]  = edge_src[e];
        attr_sorted[pos] = edge_attr4[e];
    }
}

// ---------------------------------------------------------------------------
// Merged pack kernel (proven R12): all 5 B-fragment packs in one launch.
// ---------------------------------------------------------------------------
__device__ __forceinline__ void pack_one(
    const float* __restrict__ src, __bf16* __restrict__ dst,
    int K, int KG, int N, float scale, int tid)
{
    const int lane = tid & 63;
    const int fi   = tid >> 6;
    const int g    = fi % KG;
    const int n    = fi / KG;
    const int col  = n * 16 + (lane & 15);
    const int kb   = g * 32 + 8 * (lane >> 4);
    bf16x8 v;
    #pragma unroll
    for (int i = 0; i < 8; ++i) {
        const int k = kb + i;
        v[i] = (__bf16)((k < K) ? src[(size_t)k * N + col] * scale : 0.f);
    }
    ((bf16x8*)dst)[tid] = v;
}

__global__ __launch_bounds__(256) void pack_all_kernel(
    const float* __restrict__ fc_w2,   __bf16* __restrict__ w2p,
    const float* __restrict__ sc_w0,   __bf16* __restrict__ scw0p,
    const float* __restrict__ lin2_w0, __bf16* __restrict__ l2w0p,
    const float* __restrict__ sc_w1,   __bf16* __restrict__ scw1p,
    const float* __restrict__ lin2_w1, __bf16* __restrict__ l2w1p)
{
    const int b = blockIdx.x;
    if (b < 24)      pack_one(fc_w2,   w2p,   FC_HID, 4, WNUM, RS100, b * 256 + threadIdx.x);
    else if (b < 32) pack_one(sc_w0,   scw0p, 128,    4, 128,  RS128, (b - 24) * 256 + threadIdx.x);
    else if (b < 44) pack_one(lin2_w0, l2w0p, 192,    6, 128,  RS192, (b - 32) * 256 + threadIdx.x);
    else if (b < 46) pack_one(sc_w1,   scw1p, 64,     2, 64,   RS64,  (b - 44) * 256 + threadIdx.x);
    else             pack_one(lin2_w1, l2w1p, 192,    6, 64,   RS192, (b - 46) * 256 + threadIdx.x);
}

// ---------------------------------------------------------------------------
// FUSED Kernel: MLP + weight-MFMA (into LDS stage) + gather consume.
// Block = 4 waves = 4 receivers (contiguous sorted range). Per 64-pos tile:
//  - wave mt computes h directly into A-frags in registers for its 16 edges
//    (R12-proven bit-identical math);
//  - window 0 (rows 0..32): waves 0,1 MFMA -> w_lds; barrier; all consume;
//    barrier; window 1: waves 2,3 MFMA; barrier; consume; barrier.
// Weights never touch HBM. Epilogue (angle/rbuf/rinp) verbatim R9-R12.
// ---------------------------------------------------------------------------
__global__ __launch_bounds__(256, 4) void fused_gather_kernel(
    const int* __restrict__ sorted, const int* __restrict__ head,
    const int* __restrict__ counts,
    const int* __restrict__ src_sorted, const float4* __restrict__ attr_sorted,
    const float* __restrict__ edge_scalars,
    const float* __restrict__ fc_w1, const __bf16* __restrict__ w2p,
    const __bf16* __restrict__ s_pack,
    const float* __restrict__ receiver_input, const float* __restrict__ receiver_attr,
    const float* __restrict__ lin3_w,
    __bf16* __restrict__ rbuf, __bf16* __restrict__ rinp,
    float* __restrict__ cs_arr, float* __restrict__ sn_arr)
{
    __shared__ float  fc1s[NBASIS * 128];                       // 5 KB
    __shared__ __attribute__((aligned(16))) __bf16 w_lds[32 * WSTR]; // 24.6 KB

    const int tid  = threadIdx.x;
    const int wave = tid >> 6;          // wave = m-tile index = receiver slot
    const int lane = tid & 63;
    const int p0   = blockIdx.x * 4;
    const int p    = p0 + wave;

    const int cnt   = counts[p];
    const int end   = head[p];
    const int start = end - cnt;

    const int blkStart = head[p0] - counts[p0];
    const int blkEnd   = head[p0 + 3];
    const int nT = (blkEnd - blkStart + 63) >> 6;

    for (int f = tid; f < NBASIS * FC_HID; f += 256) {
        const int i = f / FC_HID, k = f - i * FC_HID;
        fc1s[i * 128 + k] = fc_w1[f];   // reads are 4-addr broadcast: conflict-free
    }
    __syncthreads();

    const int r = lane & 15, q = lane >> 4;

    float acc[12];
    #pragma unroll
    for (int i = 0; i < 12; ++i) acc[i] = 0.f;

    for (int t64 = 0; t64 < nT; ++t64) {
        const int T = blkStart + t64 * 64;

        // ---- h -> A-frags in registers for this wave's 16 edges ----
        int gi = T + wave * 16 + r;
        if (gi >= E_N) gi = E_N - 1;    // pad rows produce garbage, never consumed
        const int eid = sorted[gi];
        float es[NBASIS];
        {
            const float2* esrc = (const float2*)(edge_scalars + (size_t)eid * NBASIS);
            #pragma unroll
            for (int i = 0; i < 5; ++i) {
                const float2 v = esrc[i];
                es[2 * i] = v.x; es[2 * i + 1] = v.y;
            }
        }
        bf16x8 a[4];
        #pragma unroll
        for (int g = 0; g < 4; ++g) {
            #pragma unroll
            for (int i2 = 0; i2 < 8; ++i2) {
                const int k = g * 32 + 8 * q + i2;
                float x = 0.f;
                if (k < FC_HID) {
                    #pragma unroll
                    for (int i = 0; i < NBASIS; ++i)
                        x = fmaf(es[i], fc1s[i * 128 + k], x);
                    x *= RS10;
                    x = x / (1.f + __expf(-x));   // silu
                }
                a[g][i2] = (__bf16)x;
            }
        }

        const bf16x8* w2v = (const bf16x8*)w2p;

        #pragma unroll
        for (int win = 0; win < 2; ++win) {
            // produce window win: waves 2*win, 2*win+1 (wave-uniform branch)
            if ((wave >> 1) == win) {
                const int rowB = (wave & 1) * 16 + 4 * q;
                #pragma unroll
                for (int tt = 0; tt < 4; ++tt) {
                    f32x4 wa[6];
                    #pragma unroll
                    for (int s = 0; s < 6; ++s) {
                        const int nt = 4 * s + tt;
                        f32x4 acc2 = {0.f, 0.f, 0.f, 0.f};
                        #pragma unroll
                        for (int g = 0; g < 4; ++g)
                            acc2 = __builtin_amdgcn_mfma_f32_16x16x32_bf16(
                                a[g], w2v[(nt * 4 + g) * 64 + lane], acc2, 0, 0, 0);
                        wa[s] = acc2;
                    }
                    const int laneP = tt * 16 + r;
                    #pragma unroll
                    for (int j = 0; j < 4; ++j) {
                        unsigned* dst = (unsigned*)((char*)w_lds
                                       + (size_t)(rowB + j) * (2 * WSTR) + laneP * 12);
                        dst[0] = pkbf(wa[0][j], wa[1][j]);
                        dst[1] = pkbf(wa[2][j], wa[3][j]);
                        dst[2] = pkbf(wa[4][j], wa[5][j]);
                    }
                }
            }
            __syncthreads();   // stage ready

            // consume positions in [T + 32*win, +32) ∩ [start, end)
            const int wLo = T + 32 * win;
            int lo = start > wLo ? start : wLo;
            int hi = end < wLo + 32 ? end : wLo + 32;
            if (lo < hi) {
                int src = src_sorted[lo];
                for (int pos = lo; pos < hi; ++pos) {
                    const int pn = (pos + 1 < hi) ? pos + 1 : hi - 1;
                    const int nsrc = src_sorted[pn];            // prefetch
                    const unsigned* wq = (const unsigned*)((const char*)w_lds
                                         + (size_t)(pos - wLo) * (2 * WSTR) + lane * 12);
                    const float4 ea = attr_sorted[pos];
                    const unsigned* sq = (const unsigned*)((const char*)s_pack
                                         + (size_t)src * 768 + lane * 12);
                    const unsigned w01 = wq[0], w23 = wq[1], w45 = wq[2];
                    const unsigned s01 = sq[0], s23 = sq[1], s45 = sq[2];

                    const float sh0 = ea.x, sh1x = ea.y, sh1y = ea.z, sh1z = ea.w;
                    const float w0a = bflo(w01), w0b = bfhi(w01);
                    const float w1a = bflo(w23), w1b = bfhi(w23);
                    const float w2w = bflo(w45), w3v = bfhi(w45);
                    const float g0a = bflo(s01), g0b = bfhi(s01);
                    const float g1x = bflo(s23), g1y = bfhi(s23), g1z = bflo(s45);

                    acc[0] = fmaf(w0a * g0a, sh0, acc[0]);
                    acc[1] = fmaf(w0b * g0b, sh0, acc[1]);
                    const float dotg = fmaf(g1x, sh1x, fmaf(g1y, sh1y, g1z * sh1z)) * RS3;
                    acc[2] = fmaf(w3v, dotg, acc[2]);
                    const float p1a = w1a * g0a, p1b = w1b * g0b;
                    acc[3] = fmaf(p1a, sh1x, acc[3]);
                    acc[4] = fmaf(p1a, sh1y, acc[4]);
                    acc[5] = fmaf(p1a, sh1z, acc[5]);
                    acc[6] = fmaf(p1b, sh1x, acc[6]);
                    acc[7] = fmaf(p1b, sh1y, acc[7]);
                    acc[8] = fmaf(p1b, sh1z, acc[8]);
                    const float qq = w2w * sh0;
                    acc[9]  = fmaf(qq, g1x, acc[9]);
                    acc[10] = fmaf(qq, g1y, acc[10]);
                    acc[11] = fmaf(qq, g1z, acc[11]);

                    src = nsrc;
                }
            }
            __syncthreads();   // consume done before stage is overwritten
        }
    }

    // ---- epilogue: angle + rbuf/rinp writes (verbatim R9-R12) ----
    const float rattr = receiver_attr[p];
    const float rfac  = RSNEI * rattr;
    const float v0 = acc[0] * rfac, v1 = acc[1] * rfac, v2 = acc[2] * rfac;

    float part = v0 * lin3_w[lane] + v1 * lin3_w[64 + lane] + v2 * lin3_w[128 + lane];
    #pragma unroll
    for (int off = 1; off < 64; off <<= 1) part += __shfl_xor(part, off);
    if (lane == 0) {
        const float a0 = part * 0.1f * RS192;
        cs_arr[p] = __cosf(a0);
        sn_arr[p] = __sinf(a0);
    }

    __bf16* rb = rbuf + (size_t)p * 768;
    rb[lane]       = (__bf16)v0;
    rb[64 + lane]  = (__bf16)v1;
    rb[128 + lane] = (__bf16)v2;
    #pragma unroll
    for (int m = 0; m < 3; ++m) {
        __bf16* r1 = rb + 192 + m * 192;
        r1[lane]        = (__bf16)(acc[3 + m] * rfac);
        r1[64 + lane]   = (__bf16)(acc[6 + m] * rfac);
        r1[128 + lane]  = (__bf16)(acc[9 + m] * rfac);
    }

    __bf16* rp = rinp + (size_t)p * 320;
    #pragma unroll
    for (int q5 = 0; q5 < 5; ++q5) {
        const int t = q5 * 64 + lane;
        const float val = receiver_input[(size_t)p * DIM + t] * rattr;
        int pos;
        if (t < 128) pos = t;
        else { const int idx = t - 128; const int u = idx / 3, m = idx - 3 * u;
               pos = 128 + m * 64 + u; }
        rp[pos] = (__bf16)val;
    }
}

// ---------------------------------------------------------------------------
// Kernel C (proven R11/R12): output transform, pure MFMA; scalar/vector split.
// ---------------------------------------------------------------------------
__global__ __launch_bounds__(256) void out_transform_kernel(
    const __bf16* __restrict__ rbuf, const __bf16* __restrict__ rinp,
    const __bf16* __restrict__ scw0p, const __bf16* __restrict__ l2w0p,
    const __bf16* __restrict__ scw1p, const __bf16* __restrict__ l2w1p,
    const float* __restrict__ cs_arr, const float* __restrict__ sn_arr,
    float* __restrict__ out, int nbS)
{
    const int wave = threadIdx.x >> 6, lane = threadIdx.x & 63;
    const bool vec = (int)blockIdx.x >= nbS;
    const int b = vec ? (int)blockIdx.x - nbS : (int)blockIdx.x;
    const int pw0 = b * 64 + wave * 16;
    const int arow = lane & 15, ag = lane >> 4;
    const int crow0 = 4 * (lane >> 4), ccol = lane & 15;

    const size_t riRow = (size_t)(pw0 + arow) * 320;
    const size_t rbRow = (size_t)(pw0 + arow) * 768;

    float cs[4], sn[4];
    #pragma unroll
    for (int j = 0; j < 4; ++j) {
        cs[j] = cs_arr[pw0 + crow0 + j];
        sn[j] = sn_arr[pw0 + crow0 + j];
    }

    if (!vec) {
        bf16x8 ain[4], arr[6];
        #pragma unroll
        for (int g = 0; g < 4; ++g)
            ain[g] = *(const bf16x8*)&rinp[riRow + g * 32 + ag * 8];
        #pragma unroll
        for (int g = 0; g < 6; ++g)
            arr[g] = *(const bf16x8*)&rbuf[rbRow + g * 32 + ag * 8];
        #pragma unroll
        for (int nt = 0; nt < 8; ++nt) {
            f32x4 asc = {0.f, 0.f, 0.f, 0.f}, acv = {0.f, 0.f, 0.f, 0.f};
            #pragma unroll
            for (int g = 0; g < 4; ++g)
                asc = __builtin_amdgcn_mfma_f32_16x16x32_bf16(
                    ain[g], ((const bf16x8*)scw0p)[(nt * 4 + g) * 64 + lane], asc, 0, 0, 0);
            #pragma unroll
            for (int g = 0; g < 6; ++g)
                acv = __builtin_amdgcn_mfma_f32_16x16x32_bf16(
                    arr[g], ((const bf16x8*)l2w0p)[(nt * 6 + g) * 64 + lane], acv, 0, 0, 0);
            #pragma unroll
            for (int j = 0; j < 4; ++j) {
                const int row = pw0 + crow0 + j;
                if (row < P_N)
                    out[(size_t)row * DIM + nt * 16 + ccol] =
                        cs[j] * asc[j] + sn[j] * acv[j];
            }
        }
    } else {
        #pragma unroll
        for (int m = 0; m < 3; ++m) {
            bf16x8 ain1[2], arr1[6];
            #pragma unroll
            for (int g = 0; g < 2; ++g)
                ain1[g] = *(const bf16x8*)&rinp[riRow + 128 + m * 64 + g * 32 + ag * 8];
            #pragma unroll
            for (int g = 0; g < 6; ++g)
                arr1[g] = *(const bf16x8*)&rbuf[rbRow + 192 + m * 192 + g * 32 + ag * 8];
            #pragma unroll
            for (int vt = 0; vt < 4; ++vt) {
                f32x4 asc = {0.f, 0.f, 0.f, 0.f}, acv = {0.f, 0.f, 0.f, 0.f};
                #pragma unroll
                for (int g = 0; g < 2; ++g)
                    asc = __builtin_amdgcn_mfma_f32_16x16x32_bf16(
                        ain1[g], ((const bf16x8*)scw1p)[(vt * 2 + g) * 64 + lane], asc, 0, 0, 0);
                #pragma unroll
                for (int g = 0; g < 6; ++g)
                    acv = __builtin_amdgcn_mfma_f32_16x16x32_bf16(
                        arr1[g], ((const bf16x8*)l2w1p)[(vt * 6 + g) * 64 + lane], acv, 0, 0, 0);
                #pragma unroll
                for (int j = 0; j < 4; ++j) {
                    const int row = pw0 + crow0 + j;
                    if (row < P_N) {
                        const int v = vt * 16 + ccol;
                        out[(size_t)row * DIM + MUL0 + 3 * v + m] =
                            cs[j] * asc[j] + sn[j] * acv[j];
                    }
                }
            }
        }
    }
}

// ---------------------------------------------------------------------------
extern "C" void kernel_launch(void* const* d_in, const int* in_sizes, int n_in,
                              void* d_out, int out_size, void* d_ws, size_t ws_size,
                              hipStream_t stream)
{
    const float* sender_input   = (const float*)d_in[0];
    const float* sender_attr    = (const float*)d_in[1];
    const float* receiver_input = (const float*)d_in[2];
    const float* receiver_attr  = (const float*)d_in[3];
    const int*   edge_src       = (const int*)  d_in[4];
    const int*   edge_dst       = (const int*)  d_in[5];
    const float* edge_attr      = (const float*)d_in[6];
    const float* edge_scalars   = (const float*)d_in[7];
    const float* fc_w1          = (const float*)d_in[8];
    const float* fc_w2          = (const float*)d_in[9];
    const float* lin1_w0        = (const float*)d_in[10];
    const float* lin1_w1        = (const float*)d_in[11];
    const float* sc_w0          = (const float*)d_in[12];
    const float* sc_w1          = (const float*)d_in[13];
    const float* lin2_w0        = (const float*)d_in[14];
    const float* lin2_w1        = (const float*)d_in[15];
    const float* lin3_w         = (const float*)d_in[16];
    float* out = (float*)d_out;

    // ws layout (~50 MB, no wbuf / no chunking):
    char* wsb = (char*)d_ws;
    float4* attr_sorted = (float4*)wsb;                                   // 3.20 MB
    __bf16* s_pack = (__bf16*)(wsb + (size_t)E_N * 16);                   // 1.54 MB
    __bf16* w2p    = s_pack + (size_t)A_N * 384;                          // 96 KB
    __bf16* scw0p  = w2p   + 24 * 4 * 64 * 8;
    __bf16* l2w0p  = scw0p +  8 * 4 * 64 * 8;
    __bf16* scw1p  = l2w0p +  8 * 6 * 64 * 8;
    __bf16* l2w1p  = scw1p +  4 * 2 * 64 * 8;
    __bf16* rbuf   = l2w1p +  4 * 6 * 64 * 8;                             // 30.8 MB
    __bf16* rinp   = rbuf + (size_t)PPAD * 768;                           // 12.8 MB
    float*  cs_arr = (float*)(rinp + (size_t)PPAD * 320);
    float*  sn_arr = cs_arr + PPAD;
    int* counts     = (int*)(sn_arr + PPAD);
    int* head       = counts + P_N;
    int* sorted     = head + P_N;
    int* src_sorted = sorted + E_N;

    sender_kernel<<<A_N, 320, 0, stream>>>(sender_input, sender_attr,
                                           lin1_w0, lin1_w1, s_pack);
    pack_all_kernel<<<52, 256, 0, stream>>>(fc_w2, w2p, sc_w0, scw0p,
                                            lin2_w0, l2w0p, sc_w1, scw1p,
                                            lin2_w1, l2w1p);

    hipMemsetAsync(counts, 0, P_N * sizeof(int), stream);
    hist_kernel<<<(E_N + 255) / 256, 256, 0, stream>>>(edge_dst, counts);
    scan_kernel<<<1, 1024, 0, stream>>>(counts, head);
    scatter_kernel<<<(E_N + 255) / 256, 256, 0, stream>>>(
        edge_dst, edge_src, (const float4*)edge_attr,
        head, sorted, src_sorted, attr_sorted);

    fused_gather_kernel<<<P_N / 4, 256, 0, stream>>>(
        sorted, head, counts, src_sorted, attr_sorted, edge_scalars,
        fc_w1, w2p, s_pack, receiver_input, receiver_attr, lin3_w,
        rbuf, rinp, cs_arr, sn_arr);

    const int nbS = PPAD / 64;   // 313
    out_transform_kernel<<<2 * nbS, 256, 0, stream>>>(
        rbuf, rinp, scw0p, l2w0p, scw1p, l2w1p, cs_arr, sn_arr, out, nbS);
}

// Round 14
// 214.063 us; speedup vs baseline: 6.3770x; 6.3770x over previous
//
#include <hip/hip_runtime.h>
#include <hip/hip_bf16.h>
#include <math.h>

// Problem constants
#define A_N    2000
#define P_N    20000
#define PPAD   20032   // P_N padded to 64 rows (out_transform tail)
#define E_N    200000
#define MUL0   128
#define MUL1   64
#define DIM    320     // MUL0 + 3*MUL1
#define NBASIS 10
#define FC_HID 100
#define WNUM   384     // 128+128+64+64
#define MID0   192     // MUL0 + MUL1
#define OV     128     // > max edges per receiver (Poisson(10), max ~30)
#define SSTRIDE 392    // stage row stride (bf16): 784 B, 16B-aligned, 4-bank shift

// scales
#define RS10   0.31622776601683794f
#define RS100  0.1f
#define RS128  0.08838834764831845f
#define RS64   0.125f
#define RS192  0.07216878364870323f
#define RS3    0.5773502691896258f
#define RSNEI  0.31622776601683794f

typedef __bf16 bf16x8 __attribute__((ext_vector_type(8)));
typedef float  f32x4  __attribute__((ext_vector_type(4)));

__device__ __forceinline__ float bflo(unsigned u) { return __uint_as_float(u << 16); }
__device__ __forceinline__ float bfhi(unsigned u) { return __uint_as_float(u & 0xffff0000u); }

// counted barriers (T3/T4 pattern): do NOT drain vmcnt -> global stores stay
// in flight across the barrier. lgkm variant publishes LDS writes first.
__device__ __forceinline__ void barrier_lgkm() {
    asm volatile("s_waitcnt lgkmcnt(0)" ::: "memory");
    __builtin_amdgcn_sched_barrier(0);
    __builtin_amdgcn_s_barrier();
    __builtin_amdgcn_sched_barrier(0);
}
__device__ __forceinline__ void barrier_raw() {
    __builtin_amdgcn_sched_barrier(0);
    __builtin_amdgcn_s_barrier();
    __builtin_amdgcn_sched_barrier(0);
}

// ---------------------------------------------------------------------------
// Generic pack helper (proven R7-R12): src [K][N] f32 -> bf16 B-fragment order.
// ---------------------------------------------------------------------------
__device__ __forceinline__ void pack_one(
    const float* __restrict__ src, __bf16* __restrict__ dst,
    int K, int KG, int N, float scale, int tid)
{
    const int lane = tid & 63;
    const int fi   = tid >> 6;
    const int g    = fi % KG;
    const int n    = fi / KG;
    const int col  = n * 16 + (lane & 15);
    const int kb   = g * 32 + 8 * (lane >> 4);
    bf16x8 v;
    #pragma unroll
    for (int i = 0; i < 8; ++i) {
        const int k = kb + i;
        v[i] = (__bf16)((k < K) ? src[(size_t)k * N + col] * scale : 0.f);
    }
    ((bf16x8*)dst)[tid] = v;
}

// ---------------------------------------------------------------------------
// FRONT kernel: sender transform (blocks 0..1999), B-frag packs (2000..2051),
// dst histogram (2052..2676). All independent; merged to cut launch gaps.
// Bodies verbatim proven R8-R12.
// ---------------------------------------------------------------------------
__global__ __launch_bounds__(320) void front_kernel(
    const float* __restrict__ sender_input, const float* __restrict__ sender_attr,
    const float* __restrict__ lin1_w0, const float* __restrict__ lin1_w1,
    __bf16* __restrict__ s_pack,
    const float* __restrict__ fc_w2,   __bf16* __restrict__ w2p,
    const float* __restrict__ sc_w0,   __bf16* __restrict__ scw0p,
    const float* __restrict__ lin2_w0, __bf16* __restrict__ l2w0p,
    const float* __restrict__ sc_w1,   __bf16* __restrict__ scw1p,
    const float* __restrict__ lin2_w1, __bf16* __restrict__ l2w1p,
    const int* __restrict__ edge_dst, int* __restrict__ counts)
{
    __shared__ float sin_s[DIM];
    const int b = blockIdx.x;
    const int t = threadIdx.x;

    if (b < A_N) {
        // ---- sender transform (proven R8-R12) ----
        const int a = b;
        const float attr = sender_attr[a];
        sin_s[t] = sender_input[(size_t)a * DIM + t] * attr;
        __syncthreads();
        __bf16* row = s_pack + (size_t)a * 384;
        if (t < MUL0) {
            float acc = 0.f;
            for (int u = 0; u < MUL0; ++u)
                acc = fmaf(sin_s[u], lin1_w0[u * MUL0 + t], acc);
            row[(t & 63) * 6 + (t >> 6)] = (__bf16)(acc * RS128);
        } else {
            const int idx = t - MUL0;
            const int v = idx / 3, m = idx - 3 * v;
            float acc = 0.f;
            for (int u = 0; u < MUL1; ++u)
                acc = fmaf(sin_s[MUL0 + 3 * u + m], lin1_w1[u * MUL1 + v], acc);
            row[v * 6 + 2 + m] = (__bf16)(acc * RS64);
        }
        if (t < 64) row[t * 6 + 5] = (__bf16)0.f;
    } else if (b < A_N + 52) {
        // ---- B-fragment packs (proven R12) ----
        if (t < 256) {
            const int bb = b - A_N;
            if (bb < 24)      pack_one(fc_w2,   w2p,   FC_HID, 4, WNUM, RS100, bb * 256 + t);
            else if (bb < 32) pack_one(sc_w0,   scw0p, 128,    4, 128,  RS128, (bb - 24) * 256 + t);
            else if (bb < 44) pack_one(lin2_w0, l2w0p, 192,    6, 128,  RS192, (bb - 32) * 256 + t);
            else if (bb < 46) pack_one(sc_w1,   scw1p, 64,     2, 64,   RS64,  (bb - 44) * 256 + t);
            else              pack_one(lin2_w1, l2w1p, 192,    6, 64,   RS192, (bb - 46) * 256 + t);
        }
    } else {
        // ---- dst histogram (proven R8-R12) ----
        const int e = (b - A_N - 52) * 320 + t;
        if (e < E_N) atomicAdd(&counts[edge_dst[e]], 1);
    }
}

// ---------------------------------------------------------------------------
// scan -> scatter (proven R8-R12)
// ---------------------------------------------------------------------------
__global__ __launch_bounds__(1024) void scan_kernel(
    const int* __restrict__ counts, int* __restrict__ head)
{
    __shared__ int part[1024];
    const int t = threadIdx.x;
    const int base = t * 20;
    int c[20];
    int s = 0;
    #pragma unroll
    for (int i = 0; i < 20; ++i) {
        const int p = base + i;
        c[i] = (p < P_N) ? counts[p] : 0;
        s += c[i];
    }
    part[t] = s;
    __syncthreads();
    for (int off = 1; off < 1024; off <<= 1) {
        const int v = (t >= off) ? part[t - off] : 0;
        __syncthreads();
        part[t] += v;
        __syncthreads();
    }
    int run = (t > 0) ? part[t - 1] : 0;
    #pragma unroll
    for (int i = 0; i < 20; ++i) {
        const int p = base + i;
        if (p < P_N) { head[p] = run; run += c[i]; }
    }
}

__global__ __launch_bounds__(256) void scatter_kernel(
    const int* __restrict__ edge_dst, const int* __restrict__ edge_src,
    const float4* __restrict__ edge_attr4,
    int* __restrict__ head, int* __restrict__ sorted,
    int* __restrict__ src_sorted, float4* __restrict__ attr_sorted)
{
    const int e = blockIdx.x * 256 + threadIdx.x;
    if (e < E_N) {
        const int pos = atomicAdd(&head[edge_dst[e]], 1);
        sorted[pos]      = e;
        src_sorted[pos]  = edge_src[e];
        attr_sorted[pos] = edge_attr4[e];
    }
}

// ---------------------------------------------------------------------------
// Kernel A (R10 body + counted barriers): MLP + weight MFMA-GEMM per chunk.
// Structure identical to R10 (proven 104 us): fc1s swizzled, es padded,
// h -> swizzled h_lds, A-frags, 2 halves of 32 rows staged in LDS then
// coalesced 768B-row stores. ONLY change: in-loop __syncthreads replaced by
// lgkm-counted / raw barriers so global stores are never drained mid-kernel.
// ---------------------------------------------------------------------------
__global__ __launch_bounds__(256) void mlp_gemm_chunk_kernel(
    const int* __restrict__ sorted,
    const float* __restrict__ edge_scalars,
    const float* __restrict__ fc_w1, const __bf16* __restrict__ w2p,
    __bf16* __restrict__ wbuf, int cLo)
{
    __shared__ float  fc1s[NBASIS * 128];      // 5 KB, swizzled
    __shared__ float  es_s[64][11];            // 2.75 KB, padded
    __shared__ int    eid_s[64];
    __shared__ __attribute__((aligned(16))) __bf16 hstage[32 * SSTRIDE]; // 24.5 KB
    // phase A: h_lds = hstage[0 .. 64*128)  (16 KB)
    // phase B: stage[32 rows][SSTRIDE] lane-blocked

    const int tid   = threadIdx.x;
    const int wave  = tid >> 6;
    const int lane  = tid & 63;
    const int pbase = blockIdx.x * 64;

    if (tid < 64) {
        int gi = cLo + pbase + tid;
        if (gi >= E_N) gi = E_N - 1;
        eid_s[tid] = sorted[gi];
    }
    for (int f = tid; f < NBASIS * FC_HID; f += 256) {
        const int i = f / FC_HID, k = f - i * FC_HID;
        fc1s[i * 128 + (k ^ ((k & 96) >> 3))] = fc_w1[f];
    }
    __syncthreads();

    for (int f = tid; f < 64 * NBASIS; f += 256) {
        const int e = f / NBASIS, i = f - e * NBASIS;
        es_s[e][i] = edge_scalars[(size_t)eid_s[e] * NBASIS + i];
    }
    __syncthreads();

    // h: thread t -> edge t>>2, k-range (t&3)*32..+31; silu; bf16 -> h_lds
    __bf16* h_lds = hstage;
    {
        const int e  = tid >> 2;
        const int k0 = (tid & 3) * 32;
        const int kx = (tid & 3) * 4;          // (k0 & 96) >> 3
        float es[NBASIS];
        #pragma unroll
        for (int i = 0; i < NBASIS; ++i) es[i] = es_s[e][i];
        #pragma unroll
        for (int o = 0; o < 4; ++o) {
            bf16x8 hv;
            #pragma unroll
            for (int j = 0; j < 8; ++j) {
                const int r = o * 8 + j;
                const int k = k0 + r;
                float x = 0.f;
                if (k < FC_HID) {
                    const int ks = k0 + (r ^ kx);   // swizzled index
                    #pragma unroll
                    for (int i = 0; i < NBASIS; ++i)
                        x = fmaf(es[i], fc1s[i * 128 + ks], x);
                    x *= RS10;
                    x = x / (1.f + __expf(-x));
                }
                hv[j] = (__bf16)x;
            }
            const int idx = (e * 128 + k0 + o * 8) ^ ((e & 7) << 3);
            *(bf16x8*)&h_lds[idx] = hv;
        }
    }
    __syncthreads();

    // A frags -> registers (proven R6-R12 layout)
    bf16x8 a[4][4];
    const int arow = lane & 15, ag = lane >> 4;
    #pragma unroll
    for (int mt = 0; mt < 4; ++mt) {
        const int e = mt * 16 + arow;
        #pragma unroll
        for (int g = 0; g < 4; ++g) {
            const int idx = (e * 128 + g * 32 + ag * 8) ^ ((e & 7) << 3);
            a[mt][g] = *(const bf16x8*)&h_lds[idx];
        }
    }
    __syncthreads();   // all A reads done before stage overwrites hstage

    const bf16x8* w2v = (const bf16x8*)w2p;
    const int row0 = 4 * (lane >> 4), col16 = lane & 15;

    #pragma unroll
    for (int half = 0; half < 2; ++half) {
        if (half) barrier_raw();   // prev-half stage reads complete (reads
                                   // were forced by issued stores); global
                                   // stores remain IN FLIGHT (no vmcnt drain)
        for (int nt = 0; nt < 6; ++nt) {
            const int ntile = wave * 6 + nt;
            bf16x8 b[4];
            #pragma unroll
            for (int g = 0; g < 4; ++g)
                b[g] = w2v[(ntile * 4 + g) * 64 + lane];
            const int L = ntile * 16 + col16;
            const int slot = (L & 63) * 6 + (L >> 6);   // lane-blocked slot
            #pragma unroll
            for (int mtl = 0; mtl < 2; ++mtl) {
                const int mt = half * 2 + mtl;
                f32x4 acc = {0.f, 0.f, 0.f, 0.f};
                #pragma unroll
                for (int g = 0; g < 4; ++g)
                    acc = __builtin_amdgcn_mfma_f32_16x16x32_bf16(a[mt][g], b[g],
                                                                  acc, 0, 0, 0);
                __bf16* sp = &hstage[(mtl * 16 + row0) * SSTRIDE + slot];
                #pragma unroll
                for (int j = 0; j < 4; ++j)
                    sp[j * SSTRIDE] = (__bf16)acc[j];
            }
        }
        barrier_lgkm();    // publish stage (LDS only; stores not drained)
        // coalesced store: 32 rows x 768B; 8 threads/row, 96B each
        const int srow = tid >> 3;
        const float4* sp4 = (const float4*)&hstage[srow * SSTRIDE + (tid & 7) * 48];
        float4* gp4 = (float4*)((char*)wbuf
                      + (size_t)(pbase + half * 32 + srow) * 768
                      + (size_t)(tid & 7) * 96);
        #pragma unroll
        for (int q = 0; q < 6; ++q) gp4[q] = sp4[q];
    }
}

// ---------------------------------------------------------------------------
// Kernel B (slim gather, proven R11/R12): depth-1 pipelined consume.
// ---------------------------------------------------------------------------
__global__ __launch_bounds__(256) void gather_kernel(
    const int* __restrict__ head, const int* __restrict__ counts,
    const int* __restrict__ src_sorted, const float4* __restrict__ attr_sorted,
    const __bf16* __restrict__ wbuf, const __bf16* __restrict__ s_pack,
    const float* __restrict__ receiver_input, const float* __restrict__ receiver_attr,
    const float* __restrict__ lin3_w,
    __bf16* __restrict__ rbuf, __bf16* __restrict__ rinp,
    float* __restrict__ cs_arr, float* __restrict__ sn_arr,
    int cLo, int cHi)
{
    __shared__ int sel_s[4];
    const int tid  = threadIdx.x;
    const int wave = tid >> 6;
    const int lane = tid & 63;
    const int p = blockIdx.x * 4 + wave;

    const int cnt   = counts[p];
    const int start = head[p] - cnt;
    const int sel   = (start >= cLo) & (start < cHi);

    if (lane == 0) sel_s[wave] = sel;
    __syncthreads();
    if ((sel_s[0] | sel_s[1] | sel_s[2] | sel_s[3]) == 0) return;
    if (!sel) return;   // no barriers below -> per-wave exit is safe

    float acc[12];
    #pragma unroll
    for (int i = 0; i < 12; ++i) acc[i] = 0.f;

    if (cnt > 0) {
        const char* wb  = (const char*)wbuf;
        const char* spk = (const char*)s_pack;
        const int last = start + cnt - 1;

        const unsigned* wq0 = (const unsigned*)(wb + (size_t)(start - cLo) * 768 + lane * 12);
        unsigned cw0 = wq0[0], cw1 = wq0[1], cw2 = wq0[2];
        float4 cea = attr_sorted[start];
        int csrc = src_sorted[start];
        const unsigned* sq0 = (const unsigned*)(spk + (size_t)csrc * 768 + lane * 12);
        unsigned cs0 = sq0[0], cs1 = sq0[1], cs2 = sq0[2];
        int nsrc = src_sorted[(start + 1 <= last) ? start + 1 : last];

        for (int i = 0; i < cnt; ++i) {
            const int pn = (start + i + 1 <= last) ? start + i + 1 : last;
            const unsigned* wqn = (const unsigned*)(wb + (size_t)(pn - cLo) * 768 + lane * 12);
            const unsigned nw0 = wqn[0], nw1 = wqn[1], nw2 = wqn[2];
            const float4 nea = attr_sorted[pn];
            const unsigned* sqn = (const unsigned*)(spk + (size_t)nsrc * 768 + lane * 12);
            const unsigned ns0 = sqn[0], ns1 = sqn[1], ns2 = sqn[2];
            int p2 = start + i + 2; if (p2 > last) p2 = last;
            const int nnsrc = src_sorted[p2];

            const float sh0 = cea.x, sh1x = cea.y, sh1y = cea.z, sh1z = cea.w;
            const float w0a = bflo(cw0), w0b = bfhi(cw0);
            const float w1a = bflo(cw1), w1b = bfhi(cw1);
            const float w2v = bflo(cw2), w3v = bfhi(cw2);
            const float g0a = bflo(cs0), g0b = bfhi(cs0);
            const float g1x = bflo(cs1), g1y = bfhi(cs1), g1z = bflo(cs2);

            acc[0] = fmaf(w0a * g0a, sh0, acc[0]);
            acc[1] = fmaf(w0b * g0b, sh0, acc[1]);
            const float dotg = fmaf(g1x, sh1x, fmaf(g1y, sh1y, g1z * sh1z)) * RS3;
            acc[2] = fmaf(w3v, dotg, acc[2]);
            const float p1a = w1a * g0a, p1b = w1b * g0b;
            acc[3] = fmaf(p1a, sh1x, acc[3]);
            acc[4] = fmaf(p1a, sh1y, acc[4]);
            acc[5] = fmaf(p1a, sh1z, acc[5]);
            acc[6] = fmaf(p1b, sh1x, acc[6]);
            acc[7] = fmaf(p1b, sh1y, acc[7]);
            acc[8] = fmaf(p1b, sh1z, acc[8]);
            const float q = w2v * sh0;
            acc[9]  = fmaf(q, g1x, acc[9]);
            acc[10] = fmaf(q, g1y, acc[10]);
            acc[11] = fmaf(q, g1z, acc[11]);

            cw0 = nw0; cw1 = nw1; cw2 = nw2;
            cs0 = ns0; cs1 = ns1; cs2 = ns2;
            cea = nea; nsrc = nnsrc;
        }
    }

    const float rattr = receiver_attr[p];
    const float rfac  = RSNEI * rattr;
    const float v0 = acc[0] * rfac, v1 = acc[1] * rfac, v2 = acc[2] * rfac;

    float part = v0 * lin3_w[lane] + v1 * lin3_w[64 + lane] + v2 * lin3_w[128 + lane];
    #pragma unroll
    for (int off = 1; off < 64; off <<= 1) part += __shfl_xor(part, off);
    if (lane == 0) {
        const float a = part * 0.1f * RS192;
        cs_arr[p] = __cosf(a);
        sn_arr[p] = __sinf(a);
    }

    __bf16* rb = rbuf + (size_t)p * 768;
    rb[lane]       = (__bf16)v0;
    rb[64 + lane]  = (__bf16)v1;
    rb[128 + lane] = (__bf16)v2;
    #pragma unroll
    for (int m = 0; m < 3; ++m) {
        __bf16* r1 = rb + 192 + m * 192;
        r1[lane]        = (__bf16)(acc[3 + m] * rfac);
        r1[64 + lane]   = (__bf16)(acc[6 + m] * rfac);
        r1[128 + lane]  = (__bf16)(acc[9 + m] * rfac);
    }

    __bf16* rp = rinp + (size_t)p * 320;
    #pragma unroll
    for (int q = 0; q < 5; ++q) {
        const int t = q * 64 + lane;
        const float val = receiver_input[(size_t)p * DIM + t] * rattr;
        int pos;
        if (t < 128) pos = t;
        else { const int idx = t - 128; const int u = idx / 3, m = idx - 3 * u;
               pos = 128 + m * 64 + u; }
        rp[pos] = (__bf16)val;
    }
}

// ---------------------------------------------------------------------------
// Kernel C (proven R11/R12): output transform, pure MFMA; scalar/vector split.
// ---------------------------------------------------------------------------
__global__ __launch_bounds__(256) void out_transform_kernel(
    const __bf16* __restrict__ rbuf, const __bf16* __restrict__ rinp,
    const __bf16* __restrict__ scw0p, const __bf16* __restrict__ l2w0p,
    const __bf16* __restrict__ scw1p, const __bf16* __restrict__ l2w1p,
    const float* __restrict__ cs_arr, const float* __restrict__ sn_arr,
    float* __restrict__ out, int nbS)
{
    const int wave = threadIdx.x >> 6, lane = threadIdx.x & 63;
    const bool vec = (int)blockIdx.x >= nbS;
    const int b = vec ? (int)blockIdx.x - nbS : (int)blockIdx.x;
    const int pw0 = b * 64 + wave * 16;
    const int arow = lane & 15, ag = lane >> 4;
    const int crow0 = 4 * (lane >> 4), ccol = lane & 15;

    const size_t riRow = (size_t)(pw0 + arow) * 320;
    const size_t rbRow = (size_t)(pw0 + arow) * 768;

    float cs[4], sn[4];
    #pragma unroll
    for (int j = 0; j < 4; ++j) {
        cs[j] = cs_arr[pw0 + crow0 + j];
        sn[j] = sn_arr[pw0 + crow0 + j];
    }

    if (!vec) {
        bf16x8 ain[4], arr[6];
        #pragma unroll
        for (int g = 0; g < 4; ++g)
            ain[g] = *(const bf16x8*)&rinp[riRow + g * 32 + ag * 8];
        #pragma unroll
        for (int g = 0; g < 6; ++g)
            arr[g] = *(const bf16x8*)&rbuf[rbRow + g * 32 + ag * 8];
        #pragma unroll
        for (int nt = 0; nt < 8; ++nt) {
            f32x4 asc = {0.f, 0.f, 0.f, 0.f}, acv = {0.f, 0.f, 0.f, 0.f};
            #pragma unroll
            for (int g = 0; g < 4; ++g)
                asc = __builtin_amdgcn_mfma_f32_16x16x32_bf16(
                    ain[g], ((const bf16x8*)scw0p)[(nt * 4 + g) * 64 + lane], asc, 0, 0, 0);
            #pragma unroll
            for (int g = 0; g < 6; ++g)
                acv = __builtin_amdgcn_mfma_f32_16x16x32_bf16(
                    arr[g], ((const bf16x8*)l2w0p)[(nt * 6 + g) * 64 + lane], acv, 0, 0, 0);
            #pragma unroll
            for (int j = 0; j < 4; ++j) {
                const int row = pw0 + crow0 + j;
                if (row < P_N)
                    out[(size_t)row * DIM + nt * 16 + ccol] =
                        cs[j] * asc[j] + sn[j] * acv[j];
            }
        }
    } else {
        #pragma unroll
        for (int m = 0; m < 3; ++m) {
            bf16x8 ain1[2], arr1[6];
            #pragma unroll
            for (int g = 0; g < 2; ++g)
                ain1[g] = *(const bf16x8*)&rinp[riRow + 128 + m * 64 + g * 32 + ag * 8];
            #pragma unroll
            for (int g = 0; g < 6; ++g)
                arr1[g] = *(const bf16x8*)&rbuf[rbRow + 192 + m * 192 + g * 32 + ag * 8];
            #pragma unroll
            for (int vt = 0; vt < 4; ++vt) {
                f32x4 asc = {0.f, 0.f, 0.f, 0.f}, acv = {0.f, 0.f, 0.f, 0.f};
                #pragma unroll
                for (int g = 0; g < 2; ++g)
                    asc = __builtin_amdgcn_mfma_f32_16x16x32_bf16(
                        ain1[g], ((const bf16x8*)scw1p)[(vt * 2 + g) * 64 + lane], asc, 0, 0, 0);
                #pragma unroll
                for (int g = 0; g < 6; ++g)
                    acv = __builtin_amdgcn_mfma_f32_16x16x32_bf16(
                        arr1[g], ((const bf16x8*)l2w1p)[(vt * 6 + g) * 64 + lane], acv, 0, 0, 0);
                #pragma unroll
                for (int j = 0; j < 4; ++j) {
                    const int row = pw0 + crow0 + j;
                    if (row < P_N) {
                        const int v = vt * 16 + ccol;
                        out[(size_t)row * DIM + MUL0 + 3 * v + m] =
                            cs[j] * asc[j] + sn[j] * acv[j];
                    }
                }
            }
        }
    }
}

// ---------------------------------------------------------------------------
extern "C" void kernel_launch(void* const* d_in, const int* in_sizes, int n_in,
                              void* d_out, int out_size, void* d_ws, size_t ws_size,
                              hipStream_t stream)
{
    const float* sender_input   = (const float*)d_in[0];
    const float* sender_attr    = (const float*)d_in[1];
    const float* receiver_input = (const float*)d_in[2];
    const float* receiver_attr  = (const float*)d_in[3];
    const int*   edge_src       = (const int*)  d_in[4];
    const int*   edge_dst       = (const int*)  d_in[5];
    const float* edge_attr      = (const float*)d_in[6];
    const float* edge_scalars   = (const float*)d_in[7];
    const float* fc_w1          = (const float*)d_in[8];
    const float* fc_w2          = (const float*)d_in[9];
    const float* lin1_w0        = (const float*)d_in[10];
    const float* lin1_w1        = (const float*)d_in[11];
    const float* sc_w0          = (const float*)d_in[12];
    const float* sc_w1          = (const float*)d_in[13];
    const float* lin2_w0        = (const float*)d_in[14];
    const float* lin2_w1        = (const float*)d_in[15];
    const float* lin3_w         = (const float*)d_in[16];
    float* out = (float*)d_out;

    // ws layout: fixed buffers first, wbuf takes the remainder.
    char* wsb = (char*)d_ws;
    float4* attr_sorted = (float4*)wsb;                                   // 3.20 MB
    __bf16* s_pack = (__bf16*)(wsb + (size_t)E_N * 16);                   // 1.54 MB
    __bf16* w2p    = s_pack + (size_t)A_N * 384;                          // 96 KB
    __bf16* scw0p  = w2p   + 24 * 4 * 64 * 8;
    __bf16* l2w0p  = scw0p +  8 * 4 * 64 * 8;
    __bf16* scw1p  = l2w0p +  8 * 6 * 64 * 8;
    __bf16* l2w1p  = scw1p +  4 * 2 * 64 * 8;
    __bf16* rbuf   = l2w1p +  4 * 6 * 64 * 8;                             // 30.8 MB
    __bf16* rinp   = rbuf + (size_t)PPAD * 768;                           // 12.8 MB
    float*  cs_arr = (float*)(rinp + (size_t)PPAD * 320);
    float*  sn_arr = cs_arr + PPAD;
    int* counts     = (int*)(sn_arr + PPAD);
    int* head       = counts + P_N;
    int* sorted     = head + P_N;
    int* src_sorted = sorted + E_N;
    __bf16* wbuf    = (__bf16*)(src_sorted + E_N);
    const size_t fixedB = (size_t)((char*)wbuf - wsb);

    // dynamic chunk size from remaining workspace (single chunk at ws>=205MB)
    long long maxpos = (long long)((ws_size - fixedB) / 768);
    long long cc = (maxpos - OV - 64) & ~63LL;
    int cchunk = (cc > E_N) ? E_N : (int)cc;

    hipMemsetAsync(counts, 0, P_N * sizeof(int), stream);
    const int histBlocks = (E_N + 319) / 320;     // 625
    front_kernel<<<A_N + 52 + histBlocks, 320, 0, stream>>>(
        sender_input, sender_attr, lin1_w0, lin1_w1, s_pack,
        fc_w2, w2p, sc_w0, scw0p, lin2_w0, l2w0p, sc_w1, scw1p,
        lin2_w1, l2w1p, edge_dst, counts);
    scan_kernel<<<1, 1024, 0, stream>>>(counts, head);
    scatter_kernel<<<(E_N + 255) / 256, 256, 0, stream>>>(
        edge_dst, edge_src, (const float4*)edge_attr,
        head, sorted, src_sorted, attr_sorted);

    for (int cLo = 0; cLo < E_N; cLo += cchunk) {
        int nPos = E_N - cLo;
        if (nPos > cchunk + OV) nPos = cchunk + OV;
        const int cHi = (cLo + cchunk >= E_N) ? (E_N + 1) : (cLo + cchunk);
        mlp_gemm_chunk_kernel<<<(nPos + 63) / 64, 256, 0, stream>>>(
            sorted, edge_scalars, fc_w1, w2p, wbuf, cLo);
        gather_kernel<<<P_N / 4, 256, 0, stream>>>(
            head, counts, src_sorted, attr_sorted, wbuf, s_pack,
            receiver_input, receiver_attr, lin3_w,
            rbuf, rinp, cs_arr, sn_arr, cLo, cHi);
    }

    const int nbS = PPAD / 64;   // 313
    out_transform_kernel<<<2 * nbS, 256, 0, stream>>>(
        rbuf, rinp, scw0p, l2w0p, scw1p, l2w1p, cs_arr, sn_arr, out, nbS);
}